// Round 1
// baseline (312.474 us; speedup 1.0000x reference)
//
#include <hip/hip_runtime.h>
#include <hip/hip_bf16.h>

// MozafariMNIST2018 forward: conv1 (28x28 full-field -> GEMM) + fire,
// conv3 (500->10 1x1) + winner-take-all.
// B=4096, T=15, HW=784, F1=500, F3=10.
//
// Output layout (float32, concatenated):
//   spk1 [4096*15*500] @ 0
//   thr1 [4096*15*500] @ 30720000
//   pot3 [4096*15*10]  @ 61440000
//   cls  [4096]        @ 62054400

typedef _Float16 f16x8 __attribute__((ext_vector_type(8)));
typedef float    f32x4 __attribute__((ext_vector_type(4)));

#define CONV1_T 26.3424f
#define BT      61440      // 4096*15
#define KDIM    784
#define F1      500

// ------------------------------------------------------------------
// Kernel 1: pot1 = A[61440x784] * W^T (w1:[500x784]), split-f16 MFMA.
// Tile: BM=128, BN=512 (full padded N, A read once), BK=32.
// 512 threads = 8 waves, wave grid 2(M) x 4(N); per-wave 64x128 output.
// ------------------------------------------------------------------
__global__ __launch_bounds__(512, 2)
void k_conv1(const float* __restrict__ inp, const float* __restrict__ w1,
             float* __restrict__ spk1, float* __restrict__ thr1)
{
    // LDS: A [128][32] f16 (8KB), B hi+lo [512][32] f16 (32KB each) = 72KB
    // Layout: half-index = row*32 + slot*8 + (k&7), slot = (k>>3) ^ ((row>>1)&3)
    __shared__ _Float16 sA[128 * 32];
    __shared__ _Float16 sB[2 * 512 * 32];

    const int tid  = threadIdx.x;
    const int lane = tid & 63;
    const int wid  = tid >> 6;     // 0..7
    const int wm   = wid >> 2;     // 0..1
    const int wn   = wid & 3;      // 0..3
    const int lr   = lane & 15;    // frag row (A) / col (B)
    const int kg   = lane >> 4;    // k-group 0..3

    const int       blkM    = blockIdx.x;           // 0..479
    const long long rowBase = (long long)blkM * 128;

    // staging roles
    const int sm  = tid >> 2;      // A row 0..127
    const int sk8 = tid & 3;       // A k-chunk 0..3
    const bool bValid = (tid < F1);

    f32x4 acc[4][8];
    #pragma unroll
    for (int i = 0; i < 4; ++i)
        #pragma unroll
        for (int j = 0; j < 8; ++j) acc[i][j] = {0.f, 0.f, 0.f, 0.f};

    // precomputed LDS frag offsets (half units); constant across K-steps
    int aOff[4];
    #pragma unroll
    for (int fm = 0; fm < 4; ++fm) {
        int r    = wm * 64 + fm * 16 + lr;
        int slot = kg ^ ((r >> 1) & 3);
        aOff[fm] = r * 32 + slot * 8;
    }
    int bOff[8];
    #pragma unroll
    for (int fn = 0; fn < 8; ++fn) {
        int n    = wn * 128 + fn * 16 + lr;
        int slot = kg ^ ((n >> 1) & 3);
        bOff[fn] = n * 32 + slot * 8;
    }

    const float* gA = inp + (rowBase + sm) * KDIM + sk8 * 8;
    const float* gB = w1 + (size_t)tid * KDIM;

    const int aSlot = sk8 ^ ((sm >> 1) & 3);
    const int aWr   = sm * 32 + aSlot * 8;

    for (int ks = 0; ks < 25; ++ks) {
        __syncthreads();
        // ---- stage A: one 16B chunk per thread
        {
            const int k0 = ks * 32 + sk8 * 8;
            f16x8 v;
            if (k0 + 8 <= KDIM) {
                const f32x4* p = (const f32x4*)(gA + ks * 32);
                f32x4 x0 = p[0], x1 = p[1];
                #pragma unroll
                for (int e = 0; e < 4; ++e) { v[e] = (_Float16)x0[e]; v[e + 4] = (_Float16)x1[e]; }
            } else {
                #pragma unroll
                for (int e = 0; e < 8; ++e) v[e] = (_Float16)0.f;
            }
            *(f16x8*)&sA[aWr] = v;
        }
        // ---- stage B hi/lo: one row (32 f16) per thread, 4 chunks
        {
            const int n = tid;
            #pragma unroll
            for (int j = 0; j < 4; ++j) {
                const int k0 = ks * 32 + j * 8;
                f16x8 hi, lo;
                if (bValid && (k0 + 8 <= KDIM)) {
                    const f32x4* p = (const f32x4*)(gB + k0);
                    f32x4 x0 = p[0], x1 = p[1];
                    #pragma unroll
                    for (int e = 0; e < 4; ++e) {
                        float w0 = x0[e], w1v = x1[e];
                        _Float16 h0 = (_Float16)w0, h1 = (_Float16)w1v;
                        hi[e]     = h0;  lo[e]     = (_Float16)(w0 - (float)h0);
                        hi[e + 4] = h1;  lo[e + 4] = (_Float16)(w1v - (float)h1);
                    }
                } else {
                    #pragma unroll
                    for (int e = 0; e < 8; ++e) { hi[e] = (_Float16)0.f; lo[e] = (_Float16)0.f; }
                }
                const int slot = j ^ ((n >> 1) & 3);
                *(f16x8*)&sB[n * 32 + slot * 8]         = hi;
                *(f16x8*)&sB[16384 + n * 32 + slot * 8] = lo;
            }
        }
        __syncthreads();
        // ---- compute: 4 A-frags held live, B hi/lo streamed per fn
        f16x8 a0 = *(const f16x8*)&sA[aOff[0]];
        f16x8 a1 = *(const f16x8*)&sA[aOff[1]];
        f16x8 a2 = *(const f16x8*)&sA[aOff[2]];
        f16x8 a3 = *(const f16x8*)&sA[aOff[3]];
        #pragma unroll
        for (int fn = 0; fn < 8; ++fn) {
            f16x8 bh = *(const f16x8*)&sB[bOff[fn]];
            f16x8 bl = *(const f16x8*)&sB[16384 + bOff[fn]];
            acc[0][fn] = __builtin_amdgcn_mfma_f32_16x16x32_f16(a0, bh, acc[0][fn], 0, 0, 0);
            acc[0][fn] = __builtin_amdgcn_mfma_f32_16x16x32_f16(a0, bl, acc[0][fn], 0, 0, 0);
            acc[1][fn] = __builtin_amdgcn_mfma_f32_16x16x32_f16(a1, bh, acc[1][fn], 0, 0, 0);
            acc[1][fn] = __builtin_amdgcn_mfma_f32_16x16x32_f16(a1, bl, acc[1][fn], 0, 0, 0);
            acc[2][fn] = __builtin_amdgcn_mfma_f32_16x16x32_f16(a2, bh, acc[2][fn], 0, 0, 0);
            acc[2][fn] = __builtin_amdgcn_mfma_f32_16x16x32_f16(a2, bl, acc[2][fn], 0, 0, 0);
            acc[3][fn] = __builtin_amdgcn_mfma_f32_16x16x32_f16(a3, bh, acc[3][fn], 0, 0, 0);
            acc[3][fn] = __builtin_amdgcn_mfma_f32_16x16x32_f16(a3, bl, acc[3][fn], 0, 0, 0);
        }
    }

    // ---- epilogue: fire. C/D layout: col = lane&15, row = (lane>>4)*4 + r
    #pragma unroll
    for (int fm = 0; fm < 4; ++fm) {
        #pragma unroll
        for (int fn = 0; fn < 8; ++fn) {
            const int n = wn * 128 + fn * 16 + lr;
            if (n < F1) {
                #pragma unroll
                for (int r = 0; r < 4; ++r) {
                    const long long m = rowBase + wm * 64 + fm * 16 + kg * 4 + r;
                    const float p  = acc[fm][fn][r];
                    const bool fire = (p >= CONV1_T);
                    thr1[m * F1 + n] = fire ? p : 0.f;
                    spk1[m * F1 + n] = fire ? 1.f : 0.f;
                }
            }
        }
    }
}

// ------------------------------------------------------------------
// Kernel 2: pot3[bt,g] = sum_f spk1[bt,f] * w3[g,f], fp32. One wave/row.
// ------------------------------------------------------------------
__global__ __launch_bounds__(256)
void k_conv3(const float* __restrict__ spk1, const float* __restrict__ w3,
             float* __restrict__ pot3)
{
    __shared__ float sw[5000];
    const int tid = threadIdx.x;
    for (int i = tid; i < 5000; i += 256) sw[i] = w3[i];
    __syncthreads();

    const int lane = tid & 63;
    const int wid  = tid >> 6;
    const long long row = (long long)blockIdx.x * 4 + wid;   // < 61440

    float ps[10];
    #pragma unroll
    for (int g = 0; g < 10; ++g) ps[g] = 0.f;

    const float* sr = spk1 + row * F1;
    #pragma unroll
    for (int j = 0; j < 8; ++j) {
        const int f = lane + 64 * j;
        if (f < F1) {
            const float s = sr[f];
            #pragma unroll
            for (int g = 0; g < 10; ++g) ps[g] += s * sw[g * F1 + f];
        }
    }
    #pragma unroll
    for (int g = 0; g < 10; ++g) {
        float v = ps[g];
        #pragma unroll
        for (int off = 32; off; off >>= 1) v += __shfl_xor(v, off);
        if (lane == 0) pot3[row * 10 + g] = v;
    }
}

// ------------------------------------------------------------------
// Kernel 3: winner-take-all per batch, faithful to reference algebra.
// ------------------------------------------------------------------
__global__ __launch_bounds__(256)
void k_winner(const float* __restrict__ pot3, float* __restrict__ outCls, int nB)
{
    const int b = blockIdx.x * 256 + threadIdx.x;
    if (b >= nB) return;
    const float* p = pot3 + (long long)b * 150 + 140;   // t = 14 row

    float pv[10], s[10];
    float mv = 0.f;   // trunc.max includes the zero entries at t != 14
    #pragma unroll
    for (int g = 0; g < 10; ++g) {
        const float v = p[g];
        pv[g] = v;
        s[g]  = (v > 0.f) ? 1.f : ((v < 0.f) ? -1.f : 0.f);
        mv = fmaxf(mv, s[g] * v);
    }
    const float vbig = mv * 15.f;
    float bm = -INFINITY; int bi = 0;
    #pragma unroll
    for (int g = 0; g < 10; ++g) {
        const float tot = s[g] * pv[g] + s[g] * vbig;
        if (tot > bm) { bm = tot; bi = g; }   // strict > keeps first index (numpy argmax)
    }
    outCls[b] = (bm != 0.f) ? (float)bi : -1.f;
}

// ------------------------------------------------------------------
extern "C" void kernel_launch(void* const* d_in, const int* in_sizes, int n_in,
                              void* d_out, int out_size, void* d_ws, size_t ws_size,
                              hipStream_t stream)
{
    const float* inp = (const float*)d_in[0];
    const float* w1  = (const float*)d_in[1];
    const float* w3  = (const float*)d_in[2];

    float* out  = (float*)d_out;
    float* spk1 = out;
    float* thr1 = out + 30720000LL;
    float* pot3 = out + 61440000LL;
    float* cls  = out + 62054400LL;

    k_conv1 <<<480, 512, 0, stream>>>(inp, w1, spk1, thr1);
    k_conv3 <<<15360, 256, 0, stream>>>(spk1, w3, pot3);
    k_winner<<<16, 256, 0, stream>>>(pot3, cls, 4096);
}

// Round 2
// 300.993 us; speedup vs baseline: 1.0381x; 1.0381x over previous
//
#include <hip/hip_runtime.h>
#include <hip/hip_bf16.h>
#include <stdint.h>

// MozafariMNIST2018 forward: conv1 (28x28 full-field -> GEMM) + fire,
// conv3 (500->10 1x1) + winner-take-all.
// B=4096, T=15, HW=784, F1=500, F3=10.
//
// Output layout (float32, concatenated):
//   spk1 [4096*15*500] @ 0
//   thr1 [4096*15*500] @ 30720000
//   pot3 [4096*15*10]  @ 61440000
//   cls  [4096]        @ 62054400
//
// Strategy: split-f16 weights (hi+lo, two MFMAs into one fp32 acc) for
// fp32-class accuracy at MFMA rate. Weights are pre-split ONCE (k_prep)
// into a global_load_lds-ready swizzled layout, staged to scratch
// (d_ws if large enough, else the pot3 region which conv3 overwrites later).
// conv1 tile 64x256, 4 waves, 36KB LDS, ~150 VGPR -> 3 blocks/CU.

typedef _Float16 f16x8 __attribute__((ext_vector_type(8)));
typedef float    f32x4 __attribute__((ext_vector_type(4)));

typedef __attribute__((address_space(3))) char        lds_char_t;
typedef const __attribute__((address_space(1))) char  gbl_char_t;

#define GLL16(gsrc, ldst) \
  __builtin_amdgcn_global_load_lds((gbl_char_t*)(gsrc), (lds_char_t*)(ldst), 16, 0, 0)

#define CONV1_T 26.3424f
#define KDIM 784
#define F1   500

// ------------------------------------------------------------------
// k_prep: split w1 [500x784] fp32 into f16 hi/lo, laid out exactly as the
// conv1 LDS tile bytes so conv1 can global_load_lds it linearly.
// Scratch layout: tile index (nb*25 + ks), 32768 B per tile.
//   Within tile, byte b: part = b>>14 (0=hi,1=lo), nl = (b&16383)>>6,
//   slot = (b>>4)&3, element e = (b>>1)&7.
//   Stored k-chunk j = slot ^ ((nl>>1)&3)  (XOR bank swizzle).
// ------------------------------------------------------------------
__global__ __launch_bounds__(256)
void k_prep(const float* __restrict__ w1, float* __restrict__ scratch)
{
    const int c = blockIdx.x * 256 + threadIdx.x;   // 0..102399, one 16B chunk
    const int tile  = c >> 11;                      // 2048 chunks per 32KB tile
    const int chunk = c & 2047;
    const int nb   = tile / 25;
    const int ks   = tile % 25;
    const int part = chunk >> 10;                   // 1024 chunks per 16KB part
    const int nl   = (chunk & 1023) >> 2;           // local row 0..255
    const int slot = chunk & 3;
    const int j    = slot ^ ((nl >> 1) & 3);
    const int k0   = ks * 32 + j * 8;
    const int ng   = nb * 256 + nl;

    f16x8 v;
    #pragma unroll
    for (int e = 0; e < 8; ++e) {
        const int kk = k0 + e;
        const float val = (ng < F1 && kk < KDIM) ? w1[ng * KDIM + kk] : 0.f;
        const _Float16 h = (_Float16)val;
        v[e] = part ? (_Float16)(val - (float)h) : h;
    }
    *(f16x8*)((char*)scratch + (size_t)c * 16) = v;
}

// ------------------------------------------------------------------
// k_conv1: pot1 = A[61440x784] * w1^T, split-f16 MFMA, fused fire.
// Tile BM=64, BN=256 (nb selects which 256-col half), BK=32.
// 256 threads = 4 waves, each wave owns a 64x64 output slice.
// ------------------------------------------------------------------
__global__ __launch_bounds__(256, 3)
void k_conv1(const float* __restrict__ inp, const float* __restrict__ bsplit,
             float* __restrict__ spk1, float* __restrict__ thr1)
{
    __shared__ _Float16 sA[64 * 32];        // 4 KB
    __shared__ _Float16 sB[2 * 256 * 32];   // 32 KB: hi @0, lo @8192 halfs

    const int tid  = threadIdx.x;
    const int lane = tid & 63;
    const int wn   = tid >> 6;      // wave 0..3 -> 64-col slice
    const int lr   = lane & 15;
    const int kg   = lane >> 4;

    // XCD-pairing swizzle: bx and bx+8 share the same A tile and (with
    // xcd = bx % 8 round-robin) land on the same XCD -> A re-read is L2-hit.
    const int bx   = blockIdx.x;                    // 0..1919
    const int nb   = (bx >> 3) & 1;
    const int mblk = ((bx >> 4) << 3) | (bx & 7);   // 0..959
    const long long rowBase = (long long)mblk * 64;

    // A staging role: thread -> (row sm, 8-wide k-chunk sk8)
    const int sm  = tid >> 2;
    const int sk8 = tid & 3;
    const int aWr = sm * 32 + (sk8 ^ ((sm >> 1) & 3)) * 8;
    const float* gA = inp + (rowBase + sm) * KDIM + sk8 * 8;

    // B: global_load_lds source (lane's 16B baked in) and LDS dest base
    const char* gB = (const char*)bsplit + (size_t)(nb * 25) * 32768 + (size_t)tid * 16;
    lds_char_t* ldsB = (lds_char_t*)(&sB[0]);
    const int wOff = wn * 1024;     // wave-uniform dest offset within 4KB chunk

    f32x4 acc[4][4];
    #pragma unroll
    for (int i = 0; i < 4; ++i)
        #pragma unroll
        for (int j2 = 0; j2 < 4; ++j2) acc[i][j2] = {0.f, 0.f, 0.f, 0.f};

    int aOff[4], bOff[4];
    #pragma unroll
    for (int fm = 0; fm < 4; ++fm) {
        const int r = fm * 16 + lr;
        aOff[fm] = r * 32 + (kg ^ ((r >> 1) & 3)) * 8;
    }
    #pragma unroll
    for (int fn = 0; fn < 4; ++fn) {
        const int n = wn * 64 + fn * 16 + lr;
        bOff[fn] = n * 32 + (kg ^ ((n >> 1) & 3)) * 8;
    }

    for (int ks = 0; ks < 25; ++ks) {
        __syncthreads();
        // ---- B: direct global->LDS, 32 KB per K-step, 8 x 4KB chunks
        {
            const char* src = gB + (size_t)ks * 32768;
            #pragma unroll
            for (int c = 0; c < 8; ++c)
                GLL16(src + c * 4096, ldsB + c * 4096 + wOff);
        }
        // ---- A: reg-stage fp32 -> f16 (binary data, exact in f16)
        {
            const int k0 = ks * 32 + sk8 * 8;
            f16x8 v;
            if (k0 + 8 <= KDIM) {
                const f32x4* p = (const f32x4*)(gA + ks * 32);
                const f32x4 x0 = p[0], x1 = p[1];
                #pragma unroll
                for (int e = 0; e < 4; ++e) { v[e] = (_Float16)x0[e]; v[e + 4] = (_Float16)x1[e]; }
            } else {
                #pragma unroll
                for (int e = 0; e < 8; ++e) v[e] = (_Float16)0.f;
            }
            *(f16x8*)&sA[aWr] = v;
        }
        __syncthreads();

        // ---- compute: 4 A-frags live, B hi/lo streamed per fn
        const f16x8 a0 = *(const f16x8*)&sA[aOff[0]];
        const f16x8 a1 = *(const f16x8*)&sA[aOff[1]];
        const f16x8 a2 = *(const f16x8*)&sA[aOff[2]];
        const f16x8 a3 = *(const f16x8*)&sA[aOff[3]];
        #pragma unroll
        for (int fn = 0; fn < 4; ++fn) {
            const f16x8 bh = *(const f16x8*)&sB[bOff[fn]];
            const f16x8 bl = *(const f16x8*)&sB[8192 + bOff[fn]];
            acc[0][fn] = __builtin_amdgcn_mfma_f32_16x16x32_f16(a0, bh, acc[0][fn], 0, 0, 0);
            acc[0][fn] = __builtin_amdgcn_mfma_f32_16x16x32_f16(a0, bl, acc[0][fn], 0, 0, 0);
            acc[1][fn] = __builtin_amdgcn_mfma_f32_16x16x32_f16(a1, bh, acc[1][fn], 0, 0, 0);
            acc[1][fn] = __builtin_amdgcn_mfma_f32_16x16x32_f16(a1, bl, acc[1][fn], 0, 0, 0);
            acc[2][fn] = __builtin_amdgcn_mfma_f32_16x16x32_f16(a2, bh, acc[2][fn], 0, 0, 0);
            acc[2][fn] = __builtin_amdgcn_mfma_f32_16x16x32_f16(a2, bl, acc[2][fn], 0, 0, 0);
            acc[3][fn] = __builtin_amdgcn_mfma_f32_16x16x32_f16(a3, bh, acc[3][fn], 0, 0, 0);
            acc[3][fn] = __builtin_amdgcn_mfma_f32_16x16x32_f16(a3, bl, acc[3][fn], 0, 0, 0);
        }
    }

    // ---- epilogue: fire. C/D layout: col = lane&15, row = (lane>>4)*4 + r
    #pragma unroll
    for (int fm = 0; fm < 4; ++fm) {
        #pragma unroll
        for (int fn = 0; fn < 4; ++fn) {
            const int ng = nb * 256 + wn * 64 + fn * 16 + lr;
            if (ng < F1) {
                #pragma unroll
                for (int r = 0; r < 4; ++r) {
                    const long long m = rowBase + fm * 16 + kg * 4 + r;
                    const float p   = acc[fm][fn][r];
                    const bool fire = (p >= CONV1_T);
                    thr1[m * F1 + ng] = fire ? p : 0.f;
                    spk1[m * F1 + ng] = fire ? 1.f : 0.f;
                }
            }
        }
    }
}

// ------------------------------------------------------------------
// k_conv3: pot3[bt,g] = sum_f spk1[bt,f] * w3[g,f], fp32. One wave/row,
// vectorized f32x4 spk1 loads (8 floats/lane).
// ------------------------------------------------------------------
__global__ __launch_bounds__(256)
void k_conv3(const float* __restrict__ spk1, const float* __restrict__ w3,
             float* __restrict__ pot3)
{
    __shared__ float sw[5000];
    const int tid = threadIdx.x;
    for (int i = tid; i < 5000; i += 256) sw[i] = w3[i];
    __syncthreads();

    const int lane = tid & 63;
    const int wr   = tid >> 6;
    const long long row = (long long)blockIdx.x * 4 + wr;   // < 61440
    const float* sr = spk1 + row * F1;

    float ps[10];
    #pragma unroll
    for (int g = 0; g < 10; ++g) ps[g] = 0.f;

    const int f0 = lane * 8;
    if (f0 < F1) {
        const f32x4 v0 = *(const f32x4*)(sr + f0);
        f32x4 v1 = {0.f, 0.f, 0.f, 0.f};
        if (f0 + 4 < F1) v1 = *(const f32x4*)(sr + f0 + 4);
        const float v[8] = {v0[0], v0[1], v0[2], v0[3], v1[0], v1[1], v1[2], v1[3]};
        #pragma unroll
        for (int e = 0; e < 8; ++e) {
            const int f = f0 + e;
            if (f < F1) {
                const float s = v[e];
                #pragma unroll
                for (int g = 0; g < 10; ++g) ps[g] += s * sw[g * F1 + f];
            }
        }
    }
    #pragma unroll
    for (int g = 0; g < 10; ++g) {
        float t = ps[g];
        #pragma unroll
        for (int off = 32; off; off >>= 1) t += __shfl_xor(t, off);
        if (lane == 0) pot3[row * 10 + g] = t;
    }
}

// ------------------------------------------------------------------
// k_winner: winner-take-all per batch, faithful to reference algebra.
// ------------------------------------------------------------------
__global__ __launch_bounds__(256)
void k_winner(const float* __restrict__ pot3, float* __restrict__ outCls, int nB)
{
    const int b = blockIdx.x * 256 + threadIdx.x;
    if (b >= nB) return;
    const float* p = pot3 + (long long)b * 150 + 140;   // t = 14 row

    float pv[10], s[10];
    float mv = 0.f;   // trunc.max includes the zero entries at t != 14
    #pragma unroll
    for (int g = 0; g < 10; ++g) {
        const float v = p[g];
        pv[g] = v;
        s[g]  = (v > 0.f) ? 1.f : ((v < 0.f) ? -1.f : 0.f);
        mv = fmaxf(mv, s[g] * v);
    }
    const float vbig = mv * 15.f;
    float bm = -INFINITY; int bi = 0;
    #pragma unroll
    for (int g = 0; g < 10; ++g) {
        const float tot = s[g] * pv[g] + s[g] * vbig;
        if (tot > bm) { bm = tot; bi = g; }   // strict > keeps first index
    }
    outCls[b] = (bm != 0.f) ? (float)bi : -1.f;
}

// ------------------------------------------------------------------
extern "C" void kernel_launch(void* const* d_in, const int* in_sizes, int n_in,
                              void* d_out, int out_size, void* d_ws, size_t ws_size,
                              hipStream_t stream)
{
    const float* inp = (const float*)d_in[0];
    const float* w1  = (const float*)d_in[1];
    const float* w3  = (const float*)d_in[2];

    float* out  = (float*)d_out;
    float* spk1 = out;
    float* thr1 = out + 30720000LL;
    float* pot3 = out + 61440000LL;
    float* cls  = out + 62054400LL;

    // Pre-split weight scratch: 2*25*32768 = 1638400 B. Prefer d_ws; else
    // borrow the pot3 region (2457600 B) — conv1 only reads it, and conv3
    // overwrites it with the real pot3 afterwards. Deterministic either way.
    float* scratch = (ws_size >= 1638400) ? (float*)d_ws : pot3;

    k_prep  <<<400,   256, 0, stream>>>(w1, scratch);
    k_conv1 <<<1920,  256, 0, stream>>>(inp, scratch, spk1, thr1);
    k_conv3 <<<15360, 256, 0, stream>>>(spk1, w3, pot3);
    k_winner<<<16,    256, 0, stream>>>(pot3, cls, 4096);
}

// Round 3
// 288.600 us; speedup vs baseline: 1.0827x; 1.0429x over previous
//
#include <hip/hip_runtime.h>
#include <hip/hip_bf16.h>
#include <stdint.h>

// MozafariMNIST2018 forward: conv1 (28x28 full-field -> GEMM) + fire,
// conv3 (500->10 1x1) + winner-take-all.
// B=4096, T=15, HW=784, F1=500, F3=10.
//
// Output layout (float32, concatenated):
//   spk1 [4096*15*500] @ 0
//   thr1 [4096*15*500] @ 30720000
//   pot3 [4096*15*10]  @ 61440000
//   cls  [4096]        @ 62054400
//
// conv1: split-f16 weights (hi+lo MFMA pairs into fp32 acc) pre-split once
// by k_prep into a global_load_lds-ready swizzled layout. Tile 128x256,
// 8 waves, double-buffered LDS (80KB, 2 blocks/CU), 2-phase prefetch
// pipeline: issue tile k+1 loads -> compute tile k -> one barrier.

typedef _Float16 f16x8 __attribute__((ext_vector_type(8)));
typedef float    f32x4 __attribute__((ext_vector_type(4)));

typedef __attribute__((address_space(3))) char        lds_char_t;
typedef const __attribute__((address_space(1))) char  gbl_char_t;

#define GLL16(gsrc, ldst) \
  __builtin_amdgcn_global_load_lds((gbl_char_t*)(gsrc), (lds_char_t*)(ldst), 16, 0, 0)

#define CONV1_T 26.3424f
#define KDIM 784
#define F1   500

// ------------------------------------------------------------------
// k_prep: split w1 [500x784] fp32 into f16 hi/lo, laid out exactly as the
// conv1 LDS tile bytes so conv1 can global_load_lds it linearly.
// Tile (nb*25+ks) is 32768 B: byte b -> part=b>>14 (0=hi,1=lo),
// nl=(b&16383)>>6, slot=(b>>4)&3, e=(b>>1)&7, k-chunk j = slot^((nl>>1)&3).
// ------------------------------------------------------------------
__global__ __launch_bounds__(256)
void k_prep(const float* __restrict__ w1, float* __restrict__ scratch)
{
    const int c = blockIdx.x * 256 + threadIdx.x;   // one 16B chunk each
    const int tile  = c >> 11;
    const int chunk = c & 2047;
    const int nb   = tile / 25;
    const int ks   = tile % 25;
    const int part = chunk >> 10;
    const int nl   = (chunk & 1023) >> 2;
    const int slot = chunk & 3;
    const int j    = slot ^ ((nl >> 1) & 3);
    const int k0   = ks * 32 + j * 8;
    const int ng   = nb * 256 + nl;

    f16x8 v;
    #pragma unroll
    for (int e = 0; e < 8; ++e) {
        const int kk = k0 + e;
        const float val = (ng < F1 && kk < KDIM) ? w1[ng * KDIM + kk] : 0.f;
        const _Float16 h = (_Float16)val;
        v[e] = part ? (_Float16)(val - (float)h) : h;
    }
    *(f16x8*)((char*)scratch + (size_t)c * 16) = v;
}

// ------------------------------------------------------------------
// k_conv1: pot1 = A[61440x784] * w1^T, split-f16 MFMA, fused fire.
// Tile BM=128, BN=256 (nb half), BK=32. 512 threads = 8 waves (2M x 4N),
// per-wave 64x64 output. Double-buffered LDS + 2-phase prefetch.
// ------------------------------------------------------------------
__global__ __launch_bounds__(512, 4)
void k_conv1(const float* __restrict__ inp, const float* __restrict__ bsplit,
             float* __restrict__ spk1, float* __restrict__ thr1)
{
    __shared__ _Float16 sA[2][128 * 32];        // 2 x 8 KB
    __shared__ _Float16 sB[2][2 * 256 * 32];    // 2 x 32 KB (hi @0, lo @8192 halfs)

    const int tid  = threadIdx.x;
    const int lane = tid & 63;
    const int wid  = tid >> 6;     // 0..7
    const int wm   = wid >> 2;     // 0..1 (M)
    const int wn   = wid & 3;      // 0..3 (N)
    const int lr   = lane & 15;
    const int kg   = lane >> 4;

    // XCD pairing: bx and bx+8 share the same A tile on the same XCD.
    const int bx   = blockIdx.x;                    // 0..959
    const int nb   = (bx >> 3) & 1;
    const int mblk = ((bx >> 4) << 3) | (bx & 7);   // 0..479
    const long long rowBase = (long long)mblk * 128;

    // A staging role: thread -> (row sm, 8-wide k-chunk sk8)
    const int sm  = tid >> 2;      // 0..127
    const int sk8 = tid & 3;
    const int aWr = sm * 32 + (sk8 ^ ((sm >> 1) & 3)) * 8;
    const float* gA = inp + (rowBase + sm) * KDIM + sk8 * 8;

    // B: global_load_lds source (lane's 16B baked in); 4 x 1KB issues per wave
    const char* gBsrc = (const char*)bsplit + (size_t)(nb * 25) * 32768
                      + (size_t)wid * 4096 + (size_t)lane * 16;

    f32x4 acc[4][4];
    #pragma unroll
    for (int i = 0; i < 4; ++i)
        #pragma unroll
        for (int j = 0; j < 4; ++j) acc[i][j] = {0.f, 0.f, 0.f, 0.f};

    int aOff[4], bOff[4];
    #pragma unroll
    for (int fm = 0; fm < 4; ++fm) {
        const int r = wm * 64 + fm * 16 + lr;
        aOff[fm] = r * 32 + (kg ^ ((r >> 1) & 3)) * 8;
    }
    #pragma unroll
    for (int fn = 0; fn < 4; ++fn) {
        const int n = wn * 64 + fn * 16 + lr;
        bOff[fn] = n * 32 + (kg ^ ((n >> 1) & 3)) * 8;
    }

    // ---- prologue: stage ks=0 into buffer 0
    {
        const f32x4 x0 = *(const f32x4*)(gA);
        const f32x4 x1 = *(const f32x4*)(gA + 4);
        #pragma unroll
        for (int i = 0; i < 4; ++i)
            GLL16(gBsrc + i * 1024, (lds_char_t*)&sB[0][0] + wid * 4096 + i * 1024);
        f16x8 v;
        #pragma unroll
        for (int e = 0; e < 4; ++e) { v[e] = (_Float16)x0[e]; v[e + 4] = (_Float16)x1[e]; }
        *(f16x8*)&sA[0][aWr] = v;
    }
    __syncthreads();

    for (int ks = 0; ks < 25; ++ks) {
        const int  cur = ks & 1;
        const bool pf  = (ks + 1 < 25);

        // ---- issue prefetch for tile ks+1 into buffer cur^1
        f32x4 x0 = {0.f, 0.f, 0.f, 0.f}, x1 = {0.f, 0.f, 0.f, 0.f};
        bool av = false;
        if (pf) {
            const int k0 = (ks + 1) * 32 + sk8 * 8;
            av = (k0 + 8 <= KDIM);
            if (av) {
                x0 = *(const f32x4*)(gA + (ks + 1) * 32);
                x1 = *(const f32x4*)(gA + (ks + 1) * 32 + 4);
            }
            const char*  src = gBsrc + (size_t)(ks + 1) * 32768;
            lds_char_t*  dst = (lds_char_t*)&sB[cur ^ 1][0] + wid * 4096;
            #pragma unroll
            for (int i = 0; i < 4; ++i)
                GLL16(src + i * 1024, dst + i * 1024);
        }

        // ---- compute tile ks from buffer cur
        const f16x8 a0 = *(const f16x8*)&sA[cur][aOff[0]];
        const f16x8 a1 = *(const f16x8*)&sA[cur][aOff[1]];
        const f16x8 a2 = *(const f16x8*)&sA[cur][aOff[2]];
        const f16x8 a3 = *(const f16x8*)&sA[cur][aOff[3]];
        #pragma unroll
        for (int fn = 0; fn < 4; ++fn) {
            const f16x8 bh = *(const f16x8*)&sB[cur][bOff[fn]];
            const f16x8 bl = *(const f16x8*)&sB[cur][8192 + bOff[fn]];
            acc[0][fn] = __builtin_amdgcn_mfma_f32_16x16x32_f16(a0, bh, acc[0][fn], 0, 0, 0);
            acc[0][fn] = __builtin_amdgcn_mfma_f32_16x16x32_f16(a0, bl, acc[0][fn], 0, 0, 0);
            acc[1][fn] = __builtin_amdgcn_mfma_f32_16x16x32_f16(a1, bh, acc[1][fn], 0, 0, 0);
            acc[1][fn] = __builtin_amdgcn_mfma_f32_16x16x32_f16(a1, bl, acc[1][fn], 0, 0, 0);
            acc[2][fn] = __builtin_amdgcn_mfma_f32_16x16x32_f16(a2, bh, acc[2][fn], 0, 0, 0);
            acc[2][fn] = __builtin_amdgcn_mfma_f32_16x16x32_f16(a2, bl, acc[2][fn], 0, 0, 0);
            acc[3][fn] = __builtin_amdgcn_mfma_f32_16x16x32_f16(a3, bh, acc[3][fn], 0, 0, 0);
            acc[3][fn] = __builtin_amdgcn_mfma_f32_16x16x32_f16(a3, bl, acc[3][fn], 0, 0, 0);
        }

        // ---- finish A prefetch: cvt + LDS write into buffer cur^1
        if (pf) {
            f16x8 v;
            #pragma unroll
            for (int e = 0; e < 4; ++e) {
                v[e]     = av ? (_Float16)x0[e] : (_Float16)0.f;
                v[e + 4] = av ? (_Float16)x1[e] : (_Float16)0.f;
            }
            *(f16x8*)&sA[cur ^ 1][aWr] = v;
        }
        __syncthreads();
    }

    // ---- epilogue: fire. C/D layout: col = lane&15, row = (lane>>4)*4 + r
    #pragma unroll
    for (int fm = 0; fm < 4; ++fm) {
        #pragma unroll
        for (int fn = 0; fn < 4; ++fn) {
            const int ng = nb * 256 + wn * 64 + fn * 16 + lr;
            if (ng < F1) {
                #pragma unroll
                for (int r = 0; r < 4; ++r) {
                    const long long m = rowBase + wm * 64 + fm * 16 + kg * 4 + r;
                    const float p   = acc[fm][fn][r];
                    const bool fire = (p >= CONV1_T);
                    thr1[m * F1 + ng] = fire ? p : 0.f;
                    spk1[m * F1 + ng] = fire ? 1.f : 0.f;
                }
            }
        }
    }
}

// ------------------------------------------------------------------
// k_conv3: pot3[bt,g] = sum_f spk1[bt,f] * w3[g,f], fp32. One wave/row,
// 8 rows per block (512 threads) to amortize the w3 LDS stage.
// ------------------------------------------------------------------
__global__ __launch_bounds__(512)
void k_conv3(const float* __restrict__ spk1, const float* __restrict__ w3,
             float* __restrict__ pot3)
{
    __shared__ float sw[5000];
    const int tid = threadIdx.x;
    for (int i = tid; i < 5000; i += 512) sw[i] = w3[i];
    __syncthreads();

    const int lane = tid & 63;
    const int wr   = tid >> 6;
    const long long row = (long long)blockIdx.x * 8 + wr;   // < 61440
    const float* sr = spk1 + row * F1;

    float ps[10];
    #pragma unroll
    for (int g = 0; g < 10; ++g) ps[g] = 0.f;

    const int f0 = lane * 8;
    if (f0 < F1) {
        const f32x4 v0 = *(const f32x4*)(sr + f0);
        f32x4 v1 = {0.f, 0.f, 0.f, 0.f};
        if (f0 + 4 < F1) v1 = *(const f32x4*)(sr + f0 + 4);
        const float v[8] = {v0[0], v0[1], v0[2], v0[3], v1[0], v1[1], v1[2], v1[3]};
        #pragma unroll
        for (int e = 0; e < 8; ++e) {
            const int f = f0 + e;
            if (f < F1) {
                const float s = v[e];
                #pragma unroll
                for (int g = 0; g < 10; ++g) ps[g] += s * sw[g * F1 + f];
            }
        }
    }
    #pragma unroll
    for (int g = 0; g < 10; ++g) {
        float t = ps[g];
        #pragma unroll
        for (int off = 32; off; off >>= 1) t += __shfl_xor(t, off);
        if (lane == 0) pot3[row * 10 + g] = t;
    }
}

// ------------------------------------------------------------------
// k_winner: winner-take-all per batch, faithful to reference algebra.
// ------------------------------------------------------------------
__global__ __launch_bounds__(256)
void k_winner(const float* __restrict__ pot3, float* __restrict__ outCls, int nB)
{
    const int b = blockIdx.x * 256 + threadIdx.x;
    if (b >= nB) return;
    const float* p = pot3 + (long long)b * 150 + 140;   // t = 14 row

    float pv[10], s[10];
    float mv = 0.f;   // trunc.max includes the zero entries at t != 14
    #pragma unroll
    for (int g = 0; g < 10; ++g) {
        const float v = p[g];
        pv[g] = v;
        s[g]  = (v > 0.f) ? 1.f : ((v < 0.f) ? -1.f : 0.f);
        mv = fmaxf(mv, s[g] * v);
    }
    const float vbig = mv * 15.f;
    float bm = -INFINITY; int bi = 0;
    #pragma unroll
    for (int g = 0; g < 10; ++g) {
        const float tot = s[g] * pv[g] + s[g] * vbig;
        if (tot > bm) { bm = tot; bi = g; }   // strict > keeps first index
    }
    outCls[b] = (bm != 0.f) ? (float)bi : -1.f;
}

// ------------------------------------------------------------------
extern "C" void kernel_launch(void* const* d_in, const int* in_sizes, int n_in,
                              void* d_out, int out_size, void* d_ws, size_t ws_size,
                              hipStream_t stream)
{
    const float* inp = (const float*)d_in[0];
    const float* w1  = (const float*)d_in[1];
    const float* w3  = (const float*)d_in[2];

    float* out  = (float*)d_out;
    float* spk1 = out;
    float* thr1 = out + 30720000LL;
    float* pot3 = out + 61440000LL;
    float* cls  = out + 62054400LL;

    // Pre-split weight scratch: 1638400 B. Prefer d_ws; else borrow the pot3
    // region (conv1 only reads it; conv3 overwrites it afterwards).
    float* scratch = (ws_size >= 1638400) ? (float*)d_ws : pot3;

    k_prep  <<<400,  256, 0, stream>>>(w1, scratch);
    k_conv1 <<<960,  512, 0, stream>>>(inp, scratch, spk1, thr1);
    k_conv3 <<<7680, 512, 0, stream>>>(spk1, w3, pot3);
    k_winner<<<16,   256, 0, stream>>>(pot3, cls, 4096);
}